// Round 2
// baseline (919.083 us; speedup 1.0000x reference)
//
#include <hip/hip_runtime.h>
#include <cmath>

#define B_   256
#define S_   100
#define D_   512
#define H_   8
#define HD_  64
#define BS_  (B_ * S_)                 // 25600 rows
#define OUT_ELEMS  (BS_ * D_)          // 13107200
#define ATTN_ELEMS (B_ * H_ * S_ * S_) // 20480000

// ---------------------------------------------------------------------------
// Wave-wide (64 lane) reductions
// ---------------------------------------------------------------------------
__device__ inline float wave_max(float v) {
    #pragma unroll
    for (int off = 32; off > 0; off >>= 1) v = fmaxf(v, __shfl_xor(v, off, 64));
    return v;
}
__device__ inline float wave_sum(float v) {
    #pragma unroll
    for (int off = 32; off > 0; off >>= 1) v += __shfl_xor(v, off, 64);
    return v;
}

// ---------------------------------------------------------------------------
// Kernel 1: QKV projection.  C[r][c] = sum_k A[r][k] * W[c][k] + bias[c]
//   A = x + pos (for Q,K) or x (for V).  z = blockIdx.z selects Q/K/V.
//   Output layout [B, H, S, HD] so attention tiles are contiguous.
//   128x128 tile, BK=8, 256 threads, 8x8 micro-tile per thread.
// ---------------------------------------------------------------------------
__global__ __launch_bounds__(256) void qkv_kernel(
    const float* __restrict__ x, const float* __restrict__ pos,
    const float* __restrict__ Wq, const float* __restrict__ bq,
    const float* __restrict__ Wk, const float* __restrict__ bk,
    const float* __restrict__ Wv, const float* __restrict__ bv,
    float* __restrict__ qws, float* __restrict__ kws, float* __restrict__ vws)
{
    const int z = blockIdx.z;
    const float* __restrict__ W    = (z == 0) ? Wq : (z == 1) ? Wk : Wv;
    const float* __restrict__ bias = (z == 0) ? bq : (z == 1) ? bk : bv;
    float* __restrict__ out        = (z == 0) ? qws : (z == 1) ? kws : vws;
    const bool addPos = (z < 2);

    // k-major LDS tiles, pitch 132 keeps float4 reads 16B-aligned (528B rows)
    __shared__ __align__(16) float As[8][132];
    __shared__ __align__(16) float Bs[8][132];

    const int t  = threadIdx.x;
    const int r0 = blockIdx.x * 128;
    const int c0 = blockIdx.y * 128;
    const int tx = t & 15, ty = t >> 4;

    const int arow = t >> 1;         // 0..127 (A row / W row within tile)
    const int ak4  = (t & 1) * 4;    // 0 or 4 (k offset of this thread's float4)
    const float* xrow = x   + (size_t)(r0 + arow) * D_;
    const float* prow = pos + (size_t)((r0 + arow) % S_) * D_;
    const float* wrow = W   + (size_t)(c0 + arow) * D_;

    float acc[8][8] = {};

    // prologue load (k0 = 0)
    float4 av = *(const float4*)(xrow + ak4);
    if (addPos) {
        float4 p = *(const float4*)(prow + ak4);
        av.x += p.x; av.y += p.y; av.z += p.z; av.w += p.w;
    }
    float4 wv = *(const float4*)(wrow + ak4);

    for (int k0 = 0; k0 < D_; k0 += 8) {
        __syncthreads();                       // previous micro-loop done
        As[ak4+0][arow] = av.x; As[ak4+1][arow] = av.y;
        As[ak4+2][arow] = av.z; As[ak4+3][arow] = av.w;
        Bs[ak4+0][arow] = wv.x; Bs[ak4+1][arow] = wv.y;
        Bs[ak4+2][arow] = wv.z; Bs[ak4+3][arow] = wv.w;
        __syncthreads();

        // prefetch next k-tile (hides HBM/L2 latency under the micro-loop)
        if (k0 + 8 < D_) {
            const int kn = k0 + 8 + ak4;
            av = *(const float4*)(xrow + kn);
            if (addPos) {
                float4 p = *(const float4*)(prow + kn);
                av.x += p.x; av.y += p.y; av.z += p.z; av.w += p.w;
            }
            wv = *(const float4*)(wrow + kn);
        }

        #pragma unroll
        for (int kk = 0; kk < 8; ++kk) {
            float4 a0 = *(const float4*)&As[kk][8*ty];
            float4 a1 = *(const float4*)&As[kk][8*ty + 4];
            float4 b0 = *(const float4*)&Bs[kk][8*tx];
            float4 b1 = *(const float4*)&Bs[kk][8*tx + 4];
            float a[8] = {a0.x,a0.y,a0.z,a0.w,a1.x,a1.y,a1.z,a1.w};
            float b[8] = {b0.x,b0.y,b0.z,b0.w,b1.x,b1.y,b1.z,b1.w};
            #pragma unroll
            for (int i = 0; i < 8; ++i)
                #pragma unroll
                for (int j = 0; j < 8; ++j)
                    acc[i][j] = fmaf(a[i], b[j], acc[i][j]);
        }
    }

    // epilogue: +bias, scatter into [B,H,S,HD]
    const int cbase = c0 + 8*tx;
    float4 bi0 = *(const float4*)(bias + cbase);
    float4 bi1 = *(const float4*)(bias + cbase + 4);
    float bb[8] = {bi0.x,bi0.y,bi0.z,bi0.w,bi1.x,bi1.y,bi1.z,bi1.w};
    const int h  = cbase >> 6;   // 8-col group never crosses a 64-wide head
    const int hd = cbase & 63;
    #pragma unroll
    for (int i = 0; i < 8; ++i) {
        int rr   = r0 + 8*ty + i;
        int bbat = rr / S_;
        int ss   = rr % S_;
        float* dst = out + (((size_t)bbat * H_ + h) * S_ + ss) * HD_ + hd;
        float4 v0 = make_float4(acc[i][0]+bb[0], acc[i][1]+bb[1],
                                acc[i][2]+bb[2], acc[i][3]+bb[3]);
        float4 v1 = make_float4(acc[i][4]+bb[4], acc[i][5]+bb[5],
                                acc[i][6]+bb[6], acc[i][7]+bb[7]);
        *(float4*)dst       = v0;
        *(float4*)(dst + 4) = v1;
    }
}

// ---------------------------------------------------------------------------
// Kernel 2: attention. One block per (b,h). Q/K/V staged in LDS.
//   decay[k]*0.125 is folded into K rows at staging (identical math to
//   scaling scores). Softmax is wave-parallel: 64 lanes own keys
//   {lane, lane+64}; shfl_xor reduce over the wave. 2 q-rows per wave pass.
//   attn written straight to d_out; ctx overwrites the Q ws region
//   (safe: Q is fully staged to LDS + __syncthreads before any ctx write,
//   and blocks only touch their own (b,h) region).
//   LDS = 81,200 B -> 2 blocks/CU on 160 KiB.
// ---------------------------------------------------------------------------
__global__ __launch_bounds__(256) void attn_kernel(
    const float* qws,                 // [B,H,S,HD]  (no __restrict__: aliases ctx)
    const float* __restrict__ kws,
    const float* __restrict__ vws,
    float* ctx,                       // == qws region
    float* __restrict__ attn_out,     // [B,H,S,S]
    const float* __restrict__ td_ptr)
{
    __shared__ float Qs[S_][64];      // broadcast-only reads, no pad needed
    __shared__ float Ks[S_][65];      // pitch 65: lane-per-key reads 2-way (free)
    __shared__ float Vs[S_][65];
    __shared__ float P[4][2][S_];     // per-wave softmax rows (2 q-rows)
    __shared__ float dec[S_];

    const int bh = blockIdx.x;
    const int t  = threadIdx.x;
    if (t < S_) dec[t] = 0.125f * powf(*td_ptr, (float)(S_ - 1 - t));
    __syncthreads();

    const float* qb = qws + (size_t)bh * (S_ * HD_);
    const float* kb = kws + (size_t)bh * (S_ * HD_);
    const float* vb = vws + (size_t)bh * (S_ * HD_);
    for (int idx = t; idx < S_ * HD_; idx += 256) {
        int row = idx >> 6, col = idx & 63;
        Qs[row][col] = qb[idx];
        Ks[row][col] = kb[idx] * dec[row];   // fold scale*decay into K
        Vs[row][col] = vb[idx];
    }
    __syncthreads();

    const int lane = t & 63, wid = t >> 6;
    const bool v1  = (lane + 64) < S_;               // lanes 0..35 own key 64+lane
    const int  k2  = v1 ? (lane + 64) : (S_ - 1);    // clamped (result masked)

    for (int qp = wid; qp < S_ / 2; qp += 4) {
        const int q0 = qp, q1 = qp + S_ / 2;
        float s00 = 0.f, s01 = 0.f, s10 = 0.f, s11 = 0.f;
        #pragma unroll 8
        for (int d = 0; d < HD_; ++d) {
            float ka = Ks[lane][d];
            float kc = Ks[k2][d];
            float qa = Qs[q0][d];
            float qc = Qs[q1][d];
            s00 = fmaf(qa, ka, s00);
            s01 = fmaf(qa, kc, s01);
            s10 = fmaf(qc, ka, s10);
            s11 = fmaf(qc, kc, s11);
        }
        if (!v1) { s01 = -3.0e38f; s11 = -3.0e38f; }
        float m0 = wave_max(fmaxf(s00, s01));
        float m1 = wave_max(fmaxf(s10, s11));
        float p00 = __expf(s00 - m0);
        float p01 = v1 ? __expf(s01 - m0) : 0.f;
        float p10 = __expf(s10 - m1);
        float p11 = v1 ? __expf(s11 - m1) : 0.f;
        float r0 = 1.f / wave_sum(p00 + p01);
        float r1 = 1.f / wave_sum(p10 + p11);
        float a00 = p00 * r0, a01 = p01 * r0;
        float a10 = p10 * r1, a11 = p11 * r1;

        size_t ab0 = (size_t)bh * (S_ * S_) + (size_t)q0 * S_;
        size_t ab1 = (size_t)bh * (S_ * S_) + (size_t)q1 * S_;
        attn_out[ab0 + lane] = a00;
        attn_out[ab1 + lane] = a10;
        if (v1) {
            attn_out[ab0 + 64 + lane] = a01;
            attn_out[ab1 + 64 + lane] = a11;
        }
        // stash P for PV (intra-wave LDS write->read, program-order safe)
        P[wid][0][lane] = a00;
        P[wid][1][lane] = a10;
        if (v1) {
            P[wid][0][64 + lane] = a01;
            P[wid][1][64 + lane] = a11;
        }

        float c0 = 0.f, c1 = 0.f;
        #pragma unroll 4
        for (int k = 0; k < S_; ++k) {
            float vv = Vs[k][lane];           // 2-way bank alias: free
            c0 = fmaf(P[wid][0][k], vv, c0);  // broadcast
            c1 = fmaf(P[wid][1][k], vv, c1);
        }
        float* cdst = ctx + (size_t)bh * (S_ * HD_);
        cdst[(size_t)q0 * HD_ + lane] = c0;
        cdst[(size_t)q1 * HD_ + lane] = c1;
    }
}

// ---------------------------------------------------------------------------
// Kernel 3: output projection.  out[r][c] = sum_d ctx[r][d] * Wo[c][d] + bo[c]
//   ctx stored as [B,H,S,HD]; A-load gathers the head-deinterleaved layout.
// ---------------------------------------------------------------------------
__global__ __launch_bounds__(256) void outproj_kernel(
    const float* __restrict__ ctx,   // [B,H,S,HD]
    const float* __restrict__ Wo, const float* __restrict__ bo,
    float* __restrict__ out)         // [B,S,D]
{
    __shared__ __align__(16) float As[8][132];
    __shared__ __align__(16) float Bs[8][132];

    const int t  = threadIdx.x;
    const int r0 = blockIdx.x * 128;
    const int c0 = blockIdx.y * 128;
    const int tx = t & 15, ty = t >> 4;

    const int arow = t >> 1;
    const int ak4  = (t & 1) * 4;
    const int r    = r0 + arow;
    const int bbat = r / S_, ss = r % S_;
    // element (r, d) = cbase[(d>>6)*S*HD + (d&63)]
    const float* cbase = ctx + (size_t)bbat * H_ * S_ * HD_ + (size_t)ss * HD_;
    const float* wrow  = Wo + (size_t)(c0 + arow) * D_;

    float acc[8][8] = {};

    float4 av = *(const float4*)(cbase + ((ak4 >> 6) * (S_ * HD_)) + (ak4 & 63));
    float4 wv = *(const float4*)(wrow + ak4);

    for (int k0 = 0; k0 < D_; k0 += 8) {
        __syncthreads();
        As[ak4+0][arow] = av.x; As[ak4+1][arow] = av.y;
        As[ak4+2][arow] = av.z; As[ak4+3][arow] = av.w;
        Bs[ak4+0][arow] = wv.x; Bs[ak4+1][arow] = wv.y;
        Bs[ak4+2][arow] = wv.z; Bs[ak4+3][arow] = wv.w;
        __syncthreads();

        if (k0 + 8 < D_) {
            const int d = k0 + 8 + ak4;
            av = *(const float4*)(cbase + ((d >> 6) * (S_ * HD_)) + (d & 63));
            wv = *(const float4*)(wrow + k0 + 8 + ak4);
        }

        #pragma unroll
        for (int kk = 0; kk < 8; ++kk) {
            float4 a0 = *(const float4*)&As[kk][8*ty];
            float4 a1 = *(const float4*)&As[kk][8*ty + 4];
            float4 b0 = *(const float4*)&Bs[kk][8*tx];
            float4 b1 = *(const float4*)&Bs[kk][8*tx + 4];
            float a[8] = {a0.x,a0.y,a0.z,a0.w,a1.x,a1.y,a1.z,a1.w};
            float b[8] = {b0.x,b0.y,b0.z,b0.w,b1.x,b1.y,b1.z,b1.w};
            #pragma unroll
            for (int i = 0; i < 8; ++i)
                #pragma unroll
                for (int j = 0; j < 8; ++j)
                    acc[i][j] = fmaf(a[i], b[j], acc[i][j]);
        }
    }

    const int cb = c0 + 8*tx;
    float4 bi0 = *(const float4*)(bo + cb);
    float4 bi1 = *(const float4*)(bo + cb + 4);
    float bb[8] = {bi0.x,bi0.y,bi0.z,bi0.w,bi1.x,bi1.y,bi1.z,bi1.w};
    #pragma unroll
    for (int i = 0; i < 8; ++i) {
        int rr = r0 + 8*ty + i;
        float* dst = out + (size_t)rr * D_ + cb;
        float4 v0 = make_float4(acc[i][0]+bb[0], acc[i][1]+bb[1],
                                acc[i][2]+bb[2], acc[i][3]+bb[3]);
        float4 v1 = make_float4(acc[i][4]+bb[4], acc[i][5]+bb[5],
                                acc[i][6]+bb[6], acc[i][7]+bb[7]);
        *(float4*)dst       = v0;
        *(float4*)(dst + 4) = v1;
    }
}

// ---------------------------------------------------------------------------
extern "C" void kernel_launch(void* const* d_in, const int* in_sizes, int n_in,
                              void* d_out, int out_size, void* d_ws, size_t ws_size,
                              hipStream_t stream) {
    (void)in_sizes; (void)n_in; (void)out_size; (void)ws_size;
    const float* x   = (const float*)d_in[0];
    const float* pos = (const float*)d_in[1];
    const float* td  = (const float*)d_in[2];
    const float* Wq  = (const float*)d_in[3];
    const float* bq  = (const float*)d_in[4];
    const float* Wk  = (const float*)d_in[5];
    const float* bk  = (const float*)d_in[6];
    const float* Wv  = (const float*)d_in[7];
    const float* bv  = (const float*)d_in[8];
    const float* Wo  = (const float*)d_in[9];
    const float* bo  = (const float*)d_in[10];

    float* out  = (float*)d_out;
    float* attn = out + (size_t)OUT_ELEMS;

    // ws: Q | K | V  (fp32, [B,H,S,HD] each) = 3 * 52.4 MB = 157,286,400 B.
    // ctx reuses Q's buffer (attention stages Q to LDS before overwriting).
    float* qws = (float*)d_ws;
    float* kws = qws + (size_t)OUT_ELEMS;
    float* vws = kws + (size_t)OUT_ELEMS;

    qkv_kernel<<<dim3(BS_ / 128, D_ / 128, 3), 256, 0, stream>>>(
        x, pos, Wq, bq, Wk, bk, Wv, bv, qws, kws, vws);
    attn_kernel<<<dim3(B_ * H_), 256, 0, stream>>>(
        qws, kws, vws, /*ctx=*/qws, attn, td);
    outproj_kernel<<<dim3(BS_ / 128, D_ / 128), 256, 0, stream>>>(
        qws, Wo, bo, out);
}

// Round 3
// 404.157 us; speedup vs baseline: 2.2741x; 2.2741x over previous
//
#include <hip/hip_runtime.h>
#include <hip/hip_bf16.h>
#include <cmath>

#define B_   256
#define S_   100
#define D_   512
#define H_   8
#define HD_  64
#define BS_  (B_ * S_)                 // 25600 rows
#define OUT_ELEMS  (BS_ * D_)          // 13107200
#define ATTN_ELEMS (B_ * H_ * S_ * S_) // 20480000
#define DD_  (D_ * D_)                 // 262144

typedef __bf16 bf16x8 __attribute__((ext_vector_type(8)));
typedef float  f32x4  __attribute__((ext_vector_type(4)));

// ---------------------------------------------------------------------------
// helpers
// ---------------------------------------------------------------------------
__device__ __forceinline__ void gload16(const void* g, void* l) {
    __builtin_amdgcn_global_load_lds(
        (const __attribute__((address_space(1))) void*)g,
        (__attribute__((address_space(3))) void*)l, 16, 0, 0);
}
__device__ __forceinline__ float blo(unsigned u) { return __uint_as_float(u << 16); }
__device__ __forceinline__ float bhi(unsigned u) { return __uint_as_float(u & 0xffff0000u); }

__device__ inline float wave_max(float v) {
    #pragma unroll
    for (int off = 32; off > 0; off >>= 1) v = fmaxf(v, __shfl_xor(v, off, 64));
    return v;
}
__device__ inline float wave_sum(float v) {
    #pragma unroll
    for (int off = 32; off > 0; off >>= 1) v += __shfl_xor(v, off, 64);
    return v;
}

// ---------------------------------------------------------------------------
// bf16 GEMM building blocks (m97 structure + T2 both-sides XOR swizzle)
// LDS tile: [128 rows][64 bf16] = 128 B/row, 8 x 16B chunks per row.
// Staged linearly by global_load_lds; SOURCE chunk is XOR-permuted by row&7,
// ds_read applies the same XOR -> 2-way bank aliasing only (free).
// ---------------------------------------------------------------------------
__device__ __forceinline__ void stage_tile(const __hip_bfloat16* __restrict__ src,
                                           char* ldsTile, int t) {
    #pragma unroll
    for (int i = 0; i < 4; ++i) {
        const int ci  = i * 256 + t;           // 16B chunk index 0..1023
        const int row = ci >> 3;               // 0..127
        const int sc  = (ci & 7) ^ (row & 7);  // inverse-swizzled source chunk
        gload16(src + (size_t)row * D_ + sc * 8,
                ldsTile + ((i * 256 + (t & 192)) << 4));  // wave-uniform base
    }
}

__device__ __forceinline__ void compute_tile(const char* ldsA, const char* ldsB,
                                             int lane, int wr, int wc,
                                             f32x4 acc[4][4]) {
    const int frow = lane & 15;
    const int fk   = lane >> 4;               // 0..3: which 16B k-quarter
    #pragma unroll
    for (int kk = 0; kk < 2; ++kk) {           // two k=32 steps per BK=64
        const int ch = kk * 4 + fk;
        bf16x8 af[4], bfr[4];
        #pragma unroll
        for (int m = 0; m < 4; ++m) {
            const int row = wr + m * 16 + frow;
            af[m] = *(const bf16x8*)(ldsA + row * 128 + ((ch ^ (row & 7)) << 4));
        }
        #pragma unroll
        for (int n = 0; n < 4; ++n) {
            const int row = wc + n * 16 + frow;
            bfr[n] = *(const bf16x8*)(ldsB + row * 128 + ((ch ^ (row & 7)) << 4));
        }
        #pragma unroll
        for (int m = 0; m < 4; ++m)
            #pragma unroll
            for (int n = 0; n < 4; ++n)
                acc[m][n] = __builtin_amdgcn_mfma_f32_16x16x32_bf16(
                    af[m], bfr[n], acc[m][n], 0, 0, 0);
    }
}

// ---------------------------------------------------------------------------
// Kernel: QKV projection via MFMA.  C = Apos @ W^T (+bias)  [z = Q,K,V]
//   V additionally subtracts pv = pos @ Wv^T (fp32), since Apos includes pos.
//   Output bf16 [B,H,S,HD].
// ---------------------------------------------------------------------------
__global__ __launch_bounds__(256) void qkv_gemm(
    const __hip_bfloat16* __restrict__ apos,
    const __hip_bfloat16* __restrict__ wall,   // Wq|Wk|Wv|Wo bf16, D*D each
    const float* __restrict__ bq, const float* __restrict__ bk,
    const float* __restrict__ bv, const float* __restrict__ pv,
    __hip_bfloat16* __restrict__ qkv)          // q|k|v, OUT_ELEMS each
{
    const int z = blockIdx.z;
    const __hip_bfloat16* W    = wall + (size_t)z * DD_;
    const float*          bias = (z == 0) ? bq : (z == 1) ? bk : bv;
    __hip_bfloat16*       out  = qkv + (size_t)z * OUT_ELEMS;

    __shared__ __align__(16) char lds[2][2][16384];   // [buf][A/B][tile]
    const int t    = threadIdx.x;
    const int r0   = blockIdx.x * 128, c0 = blockIdx.y * 128;
    const int lane = t & 63, wid = t >> 6;
    const int wr   = (wid >> 1) << 6, wc = (wid & 1) << 6;

    f32x4 acc[4][4] = {};

    const __hip_bfloat16* Ab = apos + (size_t)r0 * D_;
    const __hip_bfloat16* Bb = W    + (size_t)c0 * D_;

    stage_tile(Ab, lds[0][0], t);
    stage_tile(Bb, lds[0][1], t);
    asm volatile("s_waitcnt vmcnt(0)" ::: "memory");
    __syncthreads();

    int cur = 0;
    for (int kt = 1; kt < 8; ++kt) {
        stage_tile(Ab + kt * 64, lds[cur ^ 1][0], t);
        stage_tile(Bb + kt * 64, lds[cur ^ 1][1], t);
        compute_tile(lds[cur][0], lds[cur][1], lane, wr, wc, acc);
        asm volatile("s_waitcnt vmcnt(0)" ::: "memory");
        __syncthreads();
        cur ^= 1;
    }
    compute_tile(lds[cur][0], lds[cur][1], lane, wr, wc, acc);

    // epilogue: +bias (−pv for V), scatter bf16 into [B,H,S,HD]
    const int fcol = lane & 15, fq = lane >> 4;
    #pragma unroll
    for (int n = 0; n < 4; ++n) {
        const int c  = c0 + wc + n * 16 + fcol;
        const float bi = bias[c];
        const int h = c >> 6, hd = c & 63;
        #pragma unroll
        for (int m = 0; m < 4; ++m) {
            const int rbase = r0 + wr + m * 16 + fq * 4;
            #pragma unroll
            for (int r = 0; r < 4; ++r) {
                const int rowg = rbase + r;
                const int b = rowg / S_;
                const int s = rowg - b * S_;
                float v = acc[m][n][r] + bi;
                if (z == 2) v -= pv[s * D_ + c];
                out[(((size_t)b * H_ + h) * S_ + s) * HD_ + hd] = __float2bfloat16(v);
            }
        }
    }
}

// ---------------------------------------------------------------------------
// Kernel: output projection via MFMA.  out = ctx @ Wo^T + bo  (fp32 out)
// ---------------------------------------------------------------------------
__global__ __launch_bounds__(256) void outproj_gemm(
    const __hip_bfloat16* __restrict__ ctx,    // [BS][D] bf16 row-major
    const __hip_bfloat16* __restrict__ Wo,     // bf16 [D][D]
    const float* __restrict__ bo,
    float* __restrict__ out)                   // [BS][D] fp32
{
    __shared__ __align__(16) char lds[2][2][16384];
    const int t    = threadIdx.x;
    const int r0   = blockIdx.x * 128, c0 = blockIdx.y * 128;
    const int lane = t & 63, wid = t >> 6;
    const int wr   = (wid >> 1) << 6, wc = (wid & 1) << 6;

    f32x4 acc[4][4] = {};

    const __hip_bfloat16* Ab = ctx + (size_t)r0 * D_;
    const __hip_bfloat16* Bb = Wo  + (size_t)c0 * D_;

    stage_tile(Ab, lds[0][0], t);
    stage_tile(Bb, lds[0][1], t);
    asm volatile("s_waitcnt vmcnt(0)" ::: "memory");
    __syncthreads();

    int cur = 0;
    for (int kt = 1; kt < 8; ++kt) {
        stage_tile(Ab + kt * 64, lds[cur ^ 1][0], t);
        stage_tile(Bb + kt * 64, lds[cur ^ 1][1], t);
        compute_tile(lds[cur][0], lds[cur][1], lane, wr, wc, acc);
        asm volatile("s_waitcnt vmcnt(0)" ::: "memory");
        __syncthreads();
        cur ^= 1;
    }
    compute_tile(lds[cur][0], lds[cur][1], lane, wr, wc, acc);

    const int fcol = lane & 15, fq = lane >> 4;
    #pragma unroll
    for (int n = 0; n < 4; ++n) {
        const int c  = c0 + wc + n * 16 + fcol;
        const float bi = bo[c];
        #pragma unroll
        for (int m = 0; m < 4; ++m) {
            const int rbase = r0 + wr + m * 16 + fq * 4;
            #pragma unroll
            for (int r = 0; r < 4; ++r) {
                const int rowg = rbase + r;
                out[(size_t)rowg * D_ + c] = acc[m][n][r] + bi;
            }
        }
    }
}

// ---------------------------------------------------------------------------
// Kernel: attention (structure unchanged from passing round-1 version).
//   Reads bf16 q/k/v [B,H,S,HD]; attn fp32 to d_out; ctx bf16 [BS][D].
// ---------------------------------------------------------------------------
__global__ __launch_bounds__(256) void attn_kernel(
    const __hip_bfloat16* __restrict__ qkv,
    float* __restrict__ attn_out,              // [B,H,S,S]
    __hip_bfloat16* __restrict__ ctx,          // [BS][D]
    const float* __restrict__ td_ptr)
{
    __shared__ float Qs[S_][64];
    __shared__ float Ks[S_][65];
    __shared__ float Vs[S_][65];
    __shared__ float P[4][2][S_];
    __shared__ float dec[S_];

    const int bh = blockIdx.x;
    const int t  = threadIdx.x;
    if (t < S_) dec[t] = 0.125f * powf(*td_ptr, (float)(S_ - 1 - t));
    __syncthreads();

    const uint4* qb = (const uint4*)(qkv + (size_t)bh * (S_ * HD_));
    const uint4* kb = (const uint4*)(qkv + OUT_ELEMS + (size_t)bh * (S_ * HD_));
    const uint4* vb = (const uint4*)(qkv + 2 * (size_t)OUT_ELEMS + (size_t)bh * (S_ * HD_));
    for (int idx = t; idx < (S_ * HD_ / 8); idx += 256) {
        const int row = idx >> 3, c8 = (idx & 7) << 3;
        uint4 uq = qb[idx], uk = kb[idx], uv = vb[idx];
        const float dk = dec[row];
        Qs[row][c8+0]=blo(uq.x); Qs[row][c8+1]=bhi(uq.x);
        Qs[row][c8+2]=blo(uq.y); Qs[row][c8+3]=bhi(uq.y);
        Qs[row][c8+4]=blo(uq.z); Qs[row][c8+5]=bhi(uq.z);
        Qs[row][c8+6]=blo(uq.w); Qs[row][c8+7]=bhi(uq.w);
        Ks[row][c8+0]=blo(uk.x)*dk; Ks[row][c8+1]=bhi(uk.x)*dk;
        Ks[row][c8+2]=blo(uk.y)*dk; Ks[row][c8+3]=bhi(uk.y)*dk;
        Ks[row][c8+4]=blo(uk.z)*dk; Ks[row][c8+5]=bhi(uk.z)*dk;
        Ks[row][c8+6]=blo(uk.w)*dk; Ks[row][c8+7]=bhi(uk.w)*dk;
        Vs[row][c8+0]=blo(uv.x); Vs[row][c8+1]=bhi(uv.x);
        Vs[row][c8+2]=blo(uv.y); Vs[row][c8+3]=bhi(uv.y);
        Vs[row][c8+4]=blo(uv.z); Vs[row][c8+5]=bhi(uv.z);
        Vs[row][c8+6]=blo(uv.w); Vs[row][c8+7]=bhi(uv.w);
    }
    __syncthreads();

    const int lane = t & 63, wid = t >> 6;
    const bool v1  = (lane + 64) < S_;
    const int  k2  = v1 ? (lane + 64) : (S_ - 1);

    const int b = bh >> 3, h = bh & 7;
    __hip_bfloat16* cd = ctx + (size_t)(b * S_) * D_ + h * 64 + lane;

    for (int qp = wid; qp < S_ / 2; qp += 4) {
        const int q0 = qp, q1 = qp + S_ / 2;
        float s00 = 0.f, s01 = 0.f, s10 = 0.f, s11 = 0.f;
        #pragma unroll 8
        for (int d = 0; d < HD_; ++d) {
            float ka = Ks[lane][d];
            float kc = Ks[k2][d];
            float qa = Qs[q0][d];
            float qc = Qs[q1][d];
            s00 = fmaf(qa, ka, s00);
            s01 = fmaf(qa, kc, s01);
            s10 = fmaf(qc, ka, s10);
            s11 = fmaf(qc, kc, s11);
        }
        if (!v1) { s01 = -3.0e38f; s11 = -3.0e38f; }
        float m0 = wave_max(fmaxf(s00, s01));
        float m1 = wave_max(fmaxf(s10, s11));
        float p00 = __expf(s00 - m0);
        float p01 = v1 ? __expf(s01 - m0) : 0.f;
        float p10 = __expf(s10 - m1);
        float p11 = v1 ? __expf(s11 - m1) : 0.f;
        float r0 = 1.f / wave_sum(p00 + p01);
        float r1 = 1.f / wave_sum(p10 + p11);
        float a00 = p00 * r0, a01 = p01 * r0;
        float a10 = p10 * r1, a11 = p11 * r1;

        size_t ab0 = (size_t)bh * (S_ * S_) + (size_t)q0 * S_;
        size_t ab1 = (size_t)bh * (S_ * S_) + (size_t)q1 * S_;
        attn_out[ab0 + lane] = a00;
        attn_out[ab1 + lane] = a10;
        if (v1) {
            attn_out[ab0 + 64 + lane] = a01;
            attn_out[ab1 + 64 + lane] = a11;
        }
        P[wid][0][lane] = a00;
        P[wid][1][lane] = a10;
        if (v1) {
            P[wid][0][64 + lane] = a01;
            P[wid][1][64 + lane] = a11;
        }

        float c0 = 0.f, c1 = 0.f;
        #pragma unroll 4
        for (int k = 0; k < S_; ++k) {
            float vv = Vs[k][lane];
            c0 = fmaf(P[wid][0][k], vv, c0);
            c1 = fmaf(P[wid][1][k], vv, c1);
        }
        cd[(size_t)q0 * D_] = __float2bfloat16(c0);
        cd[(size_t)q1 * D_] = __float2bfloat16(c1);
    }
}

// ---------------------------------------------------------------------------
// Conversion / small kernels
// ---------------------------------------------------------------------------
__global__ __launch_bounds__(256) void conv_apos_kernel(
    const float* __restrict__ x, const float* __restrict__ pos,
    __hip_bfloat16* __restrict__ apos)
{
    const int i8   = (blockIdx.x * 256 + threadIdx.x) * 8;
    const int row  = i8 >> 9;
    const int prow = row % S_;
    const int pcol = i8 & 511;
    const float4* xv = (const float4*)(x + i8);
    const float4* pp = (const float4*)(pos + (size_t)prow * D_ + pcol);
    float4 a0 = xv[0], a1 = xv[1], p0 = pp[0], p1 = pp[1];
    __align__(16) __hip_bfloat16 o[8];
    o[0] = __float2bfloat16(a0.x + p0.x); o[1] = __float2bfloat16(a0.y + p0.y);
    o[2] = __float2bfloat16(a0.z + p0.z); o[3] = __float2bfloat16(a0.w + p0.w);
    o[4] = __float2bfloat16(a1.x + p1.x); o[5] = __float2bfloat16(a1.y + p1.y);
    o[6] = __float2bfloat16(a1.z + p1.z); o[7] = __float2bfloat16(a1.w + p1.w);
    *(uint4*)(apos + i8) = *(const uint4*)o;
}

__global__ __launch_bounds__(256) void conv_w_kernel(
    const float* __restrict__ Wq, const float* __restrict__ Wk,
    const float* __restrict__ Wv, const float* __restrict__ Wo,
    __hip_bfloat16* __restrict__ wall)
{
    const int z = blockIdx.y;
    const float* src = (z == 0) ? Wq : (z == 1) ? Wk : (z == 2) ? Wv : Wo;
    __hip_bfloat16* dst = wall + (size_t)z * DD_;
    const int i8 = (blockIdx.x * 256 + threadIdx.x) * 8;
    const float4* sv = (const float4*)(src + i8);
    float4 a0 = sv[0], a1 = sv[1];
    __align__(16) __hip_bfloat16 o[8];
    o[0] = __float2bfloat16(a0.x); o[1] = __float2bfloat16(a0.y);
    o[2] = __float2bfloat16(a0.z); o[3] = __float2bfloat16(a0.w);
    o[4] = __float2bfloat16(a1.x); o[5] = __float2bfloat16(a1.y);
    o[6] = __float2bfloat16(a1.z); o[7] = __float2bfloat16(a1.w);
    *(uint4*)(dst + i8) = *(const uint4*)o;
}

// pv[s][c] = sum_k pos[s][k] * Wv[c][k]   (fp32, 100x512)
__global__ __launch_bounds__(256) void posv_kernel(
    const float* __restrict__ pos, const float* __restrict__ Wv,
    float* __restrict__ pvout)
{
    const int idx = blockIdx.x * 256 + threadIdx.x;
    const int s = idx >> 9, c = idx & 511;
    const float4* pr = (const float4*)(pos + (size_t)s * D_);
    const float4* wr = (const float4*)(Wv + (size_t)c * D_);
    float a = 0.f;
    #pragma unroll 4
    for (int k = 0; k < D_ / 4; ++k) {
        float4 p = pr[k], w = wr[k];
        a = fmaf(p.x, w.x, a); a = fmaf(p.y, w.y, a);
        a = fmaf(p.z, w.z, a); a = fmaf(p.w, w.w, a);
    }
    pvout[idx] = a;
}

// ---------------------------------------------------------------------------
extern "C" void kernel_launch(void* const* d_in, const int* in_sizes, int n_in,
                              void* d_out, int out_size, void* d_ws, size_t ws_size,
                              hipStream_t stream) {
    (void)in_sizes; (void)n_in; (void)out_size; (void)ws_size;
    const float* x   = (const float*)d_in[0];
    const float* pos = (const float*)d_in[1];
    const float* td  = (const float*)d_in[2];
    const float* Wq  = (const float*)d_in[3];
    const float* bq  = (const float*)d_in[4];
    const float* Wk  = (const float*)d_in[5];
    const float* bk  = (const float*)d_in[6];
    const float* Wv  = (const float*)d_in[7];
    const float* bv  = (const float*)d_in[8];
    const float* Wo  = (const float*)d_in[9];
    const float* bo  = (const float*)d_in[10];

    float* out  = (float*)d_out;
    float* attn = out + (size_t)OUT_ELEMS;

    // ws layout (133.4 MB total; round 1 proved >=157 MB available):
    //   apos bf16 [BS][D]      @ 0          (26,214,400 B)
    //   q|k|v bf16 [B,H,S,HD]  @ 26214400   (78,643,200 B)
    //   ctx bf16 [BS][D]       @ 104857600  (26,214,400 B)
    //   W bf16 x4              @ 131072000  ( 2,097,152 B)
    //   pv fp32 [S][D]         @ 133169152  (   204,800 B)
    char* ws = (char*)d_ws;
    __hip_bfloat16* apos = (__hip_bfloat16*)ws;
    __hip_bfloat16* qkv  = (__hip_bfloat16*)(ws + 26214400);
    __hip_bfloat16* ctx  = (__hip_bfloat16*)(ws + 104857600);
    __hip_bfloat16* wall = (__hip_bfloat16*)(ws + 131072000);
    float*          pvb  = (float*)(ws + 133169152);

    conv_apos_kernel<<<OUT_ELEMS / 8 / 256, 256, 0, stream>>>(x, pos, apos);
    conv_w_kernel<<<dim3(DD_ / 8 / 256, 4), 256, 0, stream>>>(Wq, Wk, Wv, Wo, wall);
    posv_kernel<<<(S_ * D_) / 256, 256, 0, stream>>>(pos, Wv, pvb);

    qkv_gemm<<<dim3(BS_ / 128, D_ / 128, 3), 256, 0, stream>>>(
        apos, wall, bq, bk, bv, pvb, qkv);
    attn_kernel<<<B_ * H_, 256, 0, stream>>>(qkv, attn, ctx, td);
    outproj_gemm<<<dim3(BS_ / 128, D_ / 128), 256, 0, stream>>>(
        ctx, wall + 3 * (size_t)DD_, bo, out);
}

// Round 4
// 216.341 us; speedup vs baseline: 4.2483x; 1.8681x over previous
//
#include <hip/hip_runtime.h>
#include <hip/hip_bf16.h>
#include <cmath>

#define B_   256
#define S_   100
#define D_   512
#define H_   8
#define HD_  64
#define BS_  (B_ * S_)                 // 25600 rows
#define OUT_ELEMS  (BS_ * D_)          // 13107200
#define ATTN_ELEMS (B_ * H_ * S_ * S_) // 20480000
#define DD_  (D_ * D_)                 // 262144

typedef __bf16 bf16x8 __attribute__((ext_vector_type(8)));
typedef float  f32x4  __attribute__((ext_vector_type(4)));

// ---------------------------------------------------------------------------
// helpers
// ---------------------------------------------------------------------------
__device__ __forceinline__ void gload16(const void* g, void* l) {
    __builtin_amdgcn_global_load_lds(
        (const __attribute__((address_space(1))) void*)g,
        (__attribute__((address_space(3))) void*)l, 16, 0, 0);
}

// ---------------------------------------------------------------------------
// bf16 GEMM building blocks (m97 structure + T2 both-sides XOR swizzle)
// LDS tile: [128 rows][64 bf16] = 128 B/row, 8 x 16B chunks per row.
// Staged linearly by global_load_lds; SOURCE chunk is XOR-permuted by row&7,
// ds_read applies the same XOR -> 2-way bank aliasing only (free).
// ---------------------------------------------------------------------------
__device__ __forceinline__ void stage_tile(const __hip_bfloat16* __restrict__ src,
                                           char* ldsTile, int t) {
    #pragma unroll
    for (int i = 0; i < 4; ++i) {
        const int ci  = i * 256 + t;           // 16B chunk index 0..1023
        const int row = ci >> 3;               // 0..127
        const int sc  = (ci & 7) ^ (row & 7);  // inverse-swizzled source chunk
        gload16(src + (size_t)row * D_ + sc * 8,
                ldsTile + ((i * 256 + (t & 192)) << 4));  // wave-uniform base
    }
}

__device__ __forceinline__ void compute_tile(const char* ldsA, const char* ldsB,
                                             int lane, int wr, int wc,
                                             f32x4 acc[4][4]) {
    const int frow = lane & 15;
    const int fk   = lane >> 4;               // 0..3: which 16B k-quarter
    #pragma unroll
    for (int kk = 0; kk < 2; ++kk) {           // two k=32 steps per BK=64
        const int ch = kk * 4 + fk;
        bf16x8 af[4], bfr[4];
        #pragma unroll
        for (int m = 0; m < 4; ++m) {
            const int row = wr + m * 16 + frow;
            af[m] = *(const bf16x8*)(ldsA + row * 128 + ((ch ^ (row & 7)) << 4));
        }
        #pragma unroll
        for (int n = 0; n < 4; ++n) {
            const int row = wc + n * 16 + frow;
            bfr[n] = *(const bf16x8*)(ldsB + row * 128 + ((ch ^ (row & 7)) << 4));
        }
        #pragma unroll
        for (int m = 0; m < 4; ++m)
            #pragma unroll
            for (int n = 0; n < 4; ++n)
                acc[m][n] = __builtin_amdgcn_mfma_f32_16x16x32_bf16(
                    af[m], bfr[n], acc[m][n], 0, 0, 0);
    }
}

// ---------------------------------------------------------------------------
// Kernel: QKV projection via MFMA.  C = Apos @ W^T (+bias)  [z = Q,K,V]
//   V additionally subtracts pv = pos @ Wv^T (fp32), since Apos includes pos.
//   Output bf16 [B,H,S,HD].
// ---------------------------------------------------------------------------
__global__ __launch_bounds__(256) void qkv_gemm(
    const __hip_bfloat16* __restrict__ apos,
    const __hip_bfloat16* __restrict__ wall,   // Wq|Wk|Wv|Wo bf16, D*D each
    const float* __restrict__ bq, const float* __restrict__ bk,
    const float* __restrict__ bv, const float* __restrict__ pv,
    __hip_bfloat16* __restrict__ qkv)          // q|k|v, OUT_ELEMS each
{
    const int z = blockIdx.z;
    const __hip_bfloat16* W    = wall + (size_t)z * DD_;
    const float*          bias = (z == 0) ? bq : (z == 1) ? bk : bv;
    __hip_bfloat16*       out  = qkv + (size_t)z * OUT_ELEMS;

    __shared__ __align__(16) char lds[2][2][16384];   // [buf][A/B][tile]
    const int t    = threadIdx.x;
    const int r0   = blockIdx.x * 128, c0 = blockIdx.y * 128;
    const int lane = t & 63, wid = t >> 6;
    const int wr   = (wid >> 1) << 6, wc = (wid & 1) << 6;

    f32x4 acc[4][4] = {};

    const __hip_bfloat16* Ab = apos + (size_t)r0 * D_;
    const __hip_bfloat16* Bb = W    + (size_t)c0 * D_;

    stage_tile(Ab, lds[0][0], t);
    stage_tile(Bb, lds[0][1], t);
    asm volatile("s_waitcnt vmcnt(0)" ::: "memory");
    __syncthreads();

    int cur = 0;
    for (int kt = 1; kt < 8; ++kt) {
        stage_tile(Ab + kt * 64, lds[cur ^ 1][0], t);
        stage_tile(Bb + kt * 64, lds[cur ^ 1][1], t);
        compute_tile(lds[cur][0], lds[cur][1], lane, wr, wc, acc);
        asm volatile("s_waitcnt vmcnt(0)" ::: "memory");
        __syncthreads();
        cur ^= 1;
    }
    compute_tile(lds[cur][0], lds[cur][1], lane, wr, wc, acc);

    // epilogue: +bias (−pv for V), scatter bf16 into [B,H,S,HD]
    const int fcol = lane & 15, fq = lane >> 4;
    #pragma unroll
    for (int n = 0; n < 4; ++n) {
        const int c  = c0 + wc + n * 16 + fcol;
        const float bi = bias[c];
        const int h = c >> 6, hd = c & 63;
        #pragma unroll
        for (int m = 0; m < 4; ++m) {
            const int rbase = r0 + wr + m * 16 + fq * 4;
            #pragma unroll
            for (int r = 0; r < 4; ++r) {
                const int rowg = rbase + r;
                const int b = rowg / S_;
                const int s = rowg - b * S_;
                float v = acc[m][n][r] + bi;
                if (z == 2) v -= pv[s * D_ + c];
                out[(((size_t)b * H_ + h) * S_ + s) * HD_ + hd] = __float2bfloat16(v);
            }
        }
    }
}

// ---------------------------------------------------------------------------
// Kernel: output projection via MFMA.  out = ctx @ Wo^T + bo  (fp32 out)
// ---------------------------------------------------------------------------
__global__ __launch_bounds__(256) void outproj_gemm(
    const __hip_bfloat16* __restrict__ ctx,    // [BS][D] bf16 row-major
    const __hip_bfloat16* __restrict__ Wo,     // bf16 [D][D]
    const float* __restrict__ bo,
    float* __restrict__ out)                   // [BS][D] fp32
{
    __shared__ __align__(16) char lds[2][2][16384];
    const int t    = threadIdx.x;
    const int r0   = blockIdx.x * 128, c0 = blockIdx.y * 128;
    const int lane = t & 63, wid = t >> 6;
    const int wr   = (wid >> 1) << 6, wc = (wid & 1) << 6;

    f32x4 acc[4][4] = {};

    const __hip_bfloat16* Ab = ctx + (size_t)r0 * D_;
    const __hip_bfloat16* Bb = Wo  + (size_t)c0 * D_;

    stage_tile(Ab, lds[0][0], t);
    stage_tile(Bb, lds[0][1], t);
    asm volatile("s_waitcnt vmcnt(0)" ::: "memory");
    __syncthreads();

    int cur = 0;
    for (int kt = 1; kt < 8; ++kt) {
        stage_tile(Ab + kt * 64, lds[cur ^ 1][0], t);
        stage_tile(Bb + kt * 64, lds[cur ^ 1][1], t);
        compute_tile(lds[cur][0], lds[cur][1], lane, wr, wc, acc);
        asm volatile("s_waitcnt vmcnt(0)" ::: "memory");
        __syncthreads();
        cur ^= 1;
    }
    compute_tile(lds[cur][0], lds[cur][1], lane, wr, wc, acc);

    const int fcol = lane & 15, fq = lane >> 4;
    #pragma unroll
    for (int n = 0; n < 4; ++n) {
        const int c  = c0 + wc + n * 16 + fcol;
        const float bi = bo[c];
        #pragma unroll
        for (int m = 0; m < 4; ++m) {
            const int rbase = r0 + wr + m * 16 + fq * 4;
            #pragma unroll
            for (int r = 0; r < 4; ++r) {
                const int rowg = rbase + r;
                out[(size_t)rowg * D_ + c] = acc[m][n][r] + bi;
            }
        }
    }
}

// ---------------------------------------------------------------------------
// Kernel: MFMA attention. One block per 2 heads; 4 waves; 7 q-tiles/head.
//   Swapped QK^T: S^T = mfma(A=K, B=Q)  ->  col=q (lane&15), row=key.
//   Softmax over keys = 28 lane-local values + shfl_xor(16) + shfl_xor(32).
//   Decay*0.125 applied in fp32 post-MFMA; keys>=100 masked to -3e38 (P=0).
//   PV: ctx = mfma(A=P[16][136] LDS bf16, B=Vt[64][136] LDS bf16).
//   Q/K fragments read directly from global (L1-resident per head).
//   LDS 52.7 KB -> 3 blocks/CU. One barrier total (after V-transpose stage).
// ---------------------------------------------------------------------------
__global__ __launch_bounds__(256) void attn_mfma(
    const __hip_bfloat16* __restrict__ qkv,    // q|k|v [B,H,S,HD] bf16
    float* __restrict__ attn_out,              // [B,H,S,S] fp32
    __hip_bfloat16* __restrict__ ctx,          // [BS][D] bf16
    const float* __restrict__ td_ptr)
{
    __shared__ __align__(16) __hip_bfloat16 Vt[2][64][136];  // V^T per head
    __shared__ __align__(16) __hip_bfloat16 Pl[4][16][136];  // per-wave P
    __shared__ float dec[128];

    const int t    = threadIdx.x;
    const int lane = t & 63, wid = t >> 6;
    const int c    = lane & 15, g4 = lane >> 4;
    const int bh0  = blockIdx.x * 2;

    if (t < 128)
        dec[t] = (t < S_) ? 0.125f * powf(td_ptr[0], (float)(S_ - 1 - t)) : 0.f;

    // ---- stage V transposed for both heads (waves 0,1 -> head0; 2,3 -> head1)
    {
        const int h = wid >> 1;
        const int k = ((wid & 1) << 6) + lane;
        if (k < S_) {
            const __hip_bfloat16* vr = qkv + 2 * (size_t)OUT_ELEMS
                                     + (size_t)(bh0 + h) * (S_ * HD_)
                                     + (size_t)k * HD_;
            #pragma unroll
            for (int j8 = 0; j8 < 8; ++j8) {
                uint4 u = *(const uint4*)(vr + j8 * 8);
                const __hip_bfloat16* e = (const __hip_bfloat16*)&u;
                #pragma unroll
                for (int ee = 0; ee < 8; ++ee)
                    Vt[h][j8 * 8 + ee][k] = e[ee];          // 2B writes, ~2-way
            }
        }
        // zero pad keys 100..135 (so P(=0) x pad never makes NaN)
        for (int idx = t; idx < 2 * 64 * 9; idx += 256) {
            const int hh  = idx / 576;
            const int rem = idx - hh * 576;
            const int d   = rem / 9, c8 = rem - d * 9;
            *(double*)((char*)&Vt[hh][d][100] + c8 * 8) = 0.0;
        }
    }
    // zero this wave's P pad (keys 112..127) once
    *(double*)&Pl[wid][c][112 + 4 * g4] = 0.0;
    __syncthreads();

    // per-lane decay registers: key = 16*kt + 4*g4 + r
    float decr[7][4];
    #pragma unroll
    for (int kt = 0; kt < 7; ++kt)
        #pragma unroll
        for (int r = 0; r < 4; ++r)
            decr[kt][r] = dec[16 * kt + 4 * g4 + r];

    // ---- work items: 14 q-tiles (2 heads x 7), waves take (4,4,3,3)
    for (int item = wid; item < 14; item += 4) {
        const int hh = item / 7;
        const int qt = item - hh * 7;
        const int bh = bh0 + hh;
        const __hip_bfloat16* Qb = qkv + (size_t)bh * (S_ * HD_);
        const __hip_bfloat16* Kb = qkv + (size_t)OUT_ELEMS + (size_t)bh * (S_ * HD_);

        // B-operand fragments: Q rows (col=q), contiguous d
        const bf16x8 qf0 = *(const bf16x8*)(Qb + (16 * qt + c) * HD_ + 8 * g4);
        const bf16x8 qf1 = *(const bf16x8*)(Qb + (16 * qt + c) * HD_ + 32 + 8 * g4);

        // QK^T swapped: s[kt] covers keys 16kt+4g4+{0..3} at q-col c
        f32x4 s[7] = {};
        #pragma unroll
        for (int kt = 0; kt < 7; ++kt) {
            const bf16x8 kf0 = *(const bf16x8*)(Kb + (16 * kt + c) * HD_ + 8 * g4);
            const bf16x8 kf1 = *(const bf16x8*)(Kb + (16 * kt + c) * HD_ + 32 + 8 * g4);
            s[kt] = __builtin_amdgcn_mfma_f32_16x16x32_bf16(kf0, qf0, s[kt], 0, 0, 0);
            s[kt] = __builtin_amdgcn_mfma_f32_16x16x32_bf16(kf1, qf1, s[kt], 0, 0, 0);
        }

        // softmax over keys (fp32 decay+scale, index-mask, butterfly reduce)
        float m = -3.0e38f;
        #pragma unroll
        for (int kt = 0; kt < 7; ++kt)
            #pragma unroll
            for (int r = 0; r < 4; ++r) {
                float v = s[kt][r] * decr[kt][r];
                if (kt == 6 && (4 * g4 + r) >= 4) v = -3.0e38f;  // key >= 100
                s[kt][r] = v;
                m = fmaxf(m, v);
            }
        m = fmaxf(m, __shfl_xor(m, 16, 64));
        m = fmaxf(m, __shfl_xor(m, 32, 64));

        float sum = 0.f;
        #pragma unroll
        for (int kt = 0; kt < 7; ++kt)
            #pragma unroll
            for (int r = 0; r < 4; ++r) {
                const float p = __expf(s[kt][r] - m);
                s[kt][r] = p;
                sum += p;
            }
        sum += __shfl_xor(sum, 16, 64);
        sum += __shfl_xor(sum, 32, 64);
        const float rs = 1.0f / sum;

        // write attn (float4: 4 consecutive keys) + P to LDS (bf16)
        const int qg = 16 * qt + c;
        float* arow = attn_out + (size_t)bh * (S_ * S_) + (size_t)qg * S_;
        #pragma unroll
        for (int kt = 0; kt < 7; ++kt) {
            const float a0 = s[kt][0] * rs, a1 = s[kt][1] * rs;
            const float a2 = s[kt][2] * rs, a3 = s[kt][3] * rs;
            if (qg < S_ && (kt < 6 || g4 == 0))
                *(float4*)(arow + 16 * kt + 4 * g4) = make_float4(a0, a1, a2, a3);
            __align__(8) __hip_bfloat16 pb[4];
            pb[0] = __float2bfloat16(a0); pb[1] = __float2bfloat16(a1);
            pb[2] = __float2bfloat16(a2); pb[3] = __float2bfloat16(a3);
            *(double*)&Pl[wid][c][16 * kt + 4 * g4] = *(double*)pb;   // masked->0
        }

        // PV: ctx_tile[16 q][64 d] = P @ V   (A rows = q = c, B rows = Vt d-rows)
        f32x4 o[4] = {};
        #pragma unroll
        for (int kk = 0; kk < 4; ++kk) {
            const bf16x8 pf = *(const bf16x8*)&Pl[wid][c][32 * kk + 8 * g4];
            #pragma unroll
            for (int dt = 0; dt < 4; ++dt) {
                const bf16x8 vf = *(const bf16x8*)&Vt[hh][16 * dt + c][32 * kk + 8 * g4];
                o[dt] = __builtin_amdgcn_mfma_f32_16x16x32_bf16(pf, vf, o[dt], 0, 0, 0);
            }
        }

        // ctx store: row = q = 4g4+r (+16qt), col = d = 16dt+c
        const int b = bh >> 3, h = bh & 7;
        #pragma unroll
        for (int r = 0; r < 4; ++r) {
            const int q = 16 * qt + 4 * g4 + r;
            if (q < S_) {
                __hip_bfloat16* crow = ctx + (size_t)(b * S_ + q) * D_ + h * HD_ + c;
                #pragma unroll
                for (int dt = 0; dt < 4; ++dt)
                    crow[16 * dt] = __float2bfloat16(o[dt][r]);
            }
        }
    }
}

// ---------------------------------------------------------------------------
// Conversion / small kernels
// ---------------------------------------------------------------------------
__global__ __launch_bounds__(256) void conv_apos_kernel(
    const float* __restrict__ x, const float* __restrict__ pos,
    __hip_bfloat16* __restrict__ apos)
{
    const int i8   = (blockIdx.x * 256 + threadIdx.x) * 8;
    const int row  = i8 >> 9;
    const int prow = row % S_;
    const int pcol = i8 & 511;
    const float4* xv = (const float4*)(x + i8);
    const float4* pp = (const float4*)(pos + (size_t)prow * D_ + pcol);
    float4 a0 = xv[0], a1 = xv[1], p0 = pp[0], p1 = pp[1];
    __align__(16) __hip_bfloat16 o[8];
    o[0] = __float2bfloat16(a0.x + p0.x); o[1] = __float2bfloat16(a0.y + p0.y);
    o[2] = __float2bfloat16(a0.z + p0.z); o[3] = __float2bfloat16(a0.w + p0.w);
    o[4] = __float2bfloat16(a1.x + p1.x); o[5] = __float2bfloat16(a1.y + p1.y);
    o[6] = __float2bfloat16(a1.z + p1.z); o[7] = __float2bfloat16(a1.w + p1.w);
    *(uint4*)(apos + i8) = *(const uint4*)o;
}

__global__ __launch_bounds__(256) void conv_w_kernel(
    const float* __restrict__ Wq, const float* __restrict__ Wk,
    const float* __restrict__ Wv, const float* __restrict__ Wo,
    __hip_bfloat16* __restrict__ wall)
{
    const int z = blockIdx.y;
    const float* src = (z == 0) ? Wq : (z == 1) ? Wk : (z == 2) ? Wv : Wo;
    __hip_bfloat16* dst = wall + (size_t)z * DD_;
    const int i8 = (blockIdx.x * 256 + threadIdx.x) * 8;
    const float4* sv = (const float4*)(src + i8);
    float4 a0 = sv[0], a1 = sv[1];
    __align__(16) __hip_bfloat16 o[8];
    o[0] = __float2bfloat16(a0.x); o[1] = __float2bfloat16(a0.y);
    o[2] = __float2bfloat16(a0.z); o[3] = __float2bfloat16(a0.w);
    o[4] = __float2bfloat16(a1.x); o[5] = __float2bfloat16(a1.y);
    o[6] = __float2bfloat16(a1.z); o[7] = __float2bfloat16(a1.w);
    *(uint4*)(dst + i8) = *(const uint4*)o;
}

// pv[s][c] = sum_k pos[s][k] * Wv[c][k]   (fp32, 100x512)
__global__ __launch_bounds__(256) void posv_kernel(
    const float* __restrict__ pos, const float* __restrict__ Wv,
    float* __restrict__ pvout)
{
    const int idx = blockIdx.x * 256 + threadIdx.x;
    const int s = idx >> 9, c = idx & 511;
    const float4* pr = (const float4*)(pos + (size_t)s * D_);
    const float4* wr = (const float4*)(Wv + (size_t)c * D_);
    float a = 0.f;
    #pragma unroll 4
    for (int k = 0; k < D_ / 4; ++k) {
        float4 p = pr[k], w = wr[k];
        a = fmaf(p.x, w.x, a); a = fmaf(p.y, w.y, a);
        a = fmaf(p.z, w.z, a); a = fmaf(p.w, w.w, a);
    }
    pvout[idx] = a;
}

// ---------------------------------------------------------------------------
extern "C" void kernel_launch(void* const* d_in, const int* in_sizes, int n_in,
                              void* d_out, int out_size, void* d_ws, size_t ws_size,
                              hipStream_t stream) {
    (void)in_sizes; (void)n_in; (void)out_size; (void)ws_size;
    const float* x   = (const float*)d_in[0];
    const float* pos = (const float*)d_in[1];
    const float* td  = (const float*)d_in[2];
    const float* Wq  = (const float*)d_in[3];
    const float* bq  = (const float*)d_in[4];
    const float* Wk  = (const float*)d_in[5];
    const float* bk  = (const float*)d_in[6];
    const float* Wv  = (const float*)d_in[7];
    const float* bv  = (const float*)d_in[8];
    const float* Wo  = (const float*)d_in[9];
    const float* bo  = (const float*)d_in[10];

    float* out  = (float*)d_out;
    float* attn = out + (size_t)OUT_ELEMS;

    // ws layout (133.4 MB total; round 1 proved >=157 MB available):
    //   apos bf16 [BS][D]      @ 0          (26,214,400 B)
    //   q|k|v bf16 [B,H,S,HD]  @ 26214400   (78,643,200 B)
    //   ctx bf16 [BS][D]       @ 104857600  (26,214,400 B)
    //   W bf16 x4              @ 131072000  ( 2,097,152 B)
    //   pv fp32 [S][D]         @ 133169152  (   204,800 B)
    char* ws = (char*)d_ws;
    __hip_bfloat16* apos = (__hip_bfloat16*)ws;
    __hip_bfloat16* qkv  = (__hip_bfloat16*)(ws + 26214400);
    __hip_bfloat16* ctx  = (__hip_bfloat16*)(ws + 104857600);
    __hip_bfloat16* wall = (__hip_bfloat16*)(ws + 131072000);
    float*          pvb  = (float*)(ws + 133169152);

    conv_apos_kernel<<<OUT_ELEMS / 8 / 256, 256, 0, stream>>>(x, pos, apos);
    conv_w_kernel<<<dim3(DD_ / 8 / 256, 4), 256, 0, stream>>>(Wq, Wk, Wv, Wo, wall);
    posv_kernel<<<(S_ * D_) / 256, 256, 0, stream>>>(pos, Wv, pvb);

    qkv_gemm<<<dim3(BS_ / 128, D_ / 128, 3), 256, 0, stream>>>(
        apos, wall, bq, bk, bv, pvb, qkv);
    attn_mfma<<<B_ * H_ / 2, 256, 0, stream>>>(qkv, attn, ctx, td);
    outproj_gemm<<<dim3(BS_ / 128, D_ / 128), 256, 0, stream>>>(
        ctx, wall + 3 * (size_t)DD_, bo, out);
}